// Round 9
// baseline (512.595 us; speedup 1.0000x reference)
//
#include <hip/hip_runtime.h>
#include <hip/hip_bf16.h>

typedef __attribute__((ext_vector_type(8))) short short8;   // 8 bf16 (4 VGPRs)
typedef __attribute__((ext_vector_type(4))) float f32x4;    // MFMA 16x16 C/D
typedef __attribute__((ext_vector_type(16))) float f32x16;  // MFMA 32x32 C/D

#define NB 8
#define NC 256
#define NN 4096
#define ND 32
#define NCH 16   // j-chunks of 256
#define LOG2E 1.44269504088896340736f

// P tile [2][128][256] ushort, 16B-slot XOR swizzle (validated R8: conflicts
// 8.4M -> 2.1M). row<<8 + (col ^ ((row&15)<<3)).
#define PIDX(row, col) (((row) << 8) + ((col) ^ (((row) & 15) << 3)))

static __device__ __forceinline__ ushort f2bf(float f) {
  __hip_bfloat16 h = __float2bfloat16(f);
  return reinterpret_cast<ushort&>(h);
}

// ---------------------------------------------------------------------------
// Projection (unchanged from R6-R8): fp32 MAC, bf16 out; Q pre-scaled log2e.
//   blockIdx.y==0 : o in [0,64)  -> QK[b][n][64]  (q 0..31, k 32..63)
//   blockIdx.y>=1 : o in [64,320)-> Vt[b][o-64][n]  (V transposed, bf16)
// ---------------------------------------------------------------------------
__global__ __launch_bounds__(256, 4)
void proj_kernel(const float* __restrict__ x,
                 const float* __restrict__ wq, const float* __restrict__ bq,
                 const float* __restrict__ wk, const float* __restrict__ bk,
                 const float* __restrict__ wv, const float* __restrict__ bv,
                 ushort* __restrict__ qk, ushort* __restrict__ vt) {
  __shared__ float Xs[16][128];
  __shared__ float Ws[16][64];
  const int n0 = blockIdx.x * 128;
  const int o0 = blockIdx.y * 64;
  const int b  = blockIdx.z;
  const int t  = threadIdx.x;
  const int og4 = t & 15;
  const int ng  = t >> 4;

  float acc[4][8];
#pragma unroll
  for (int i = 0; i < 4; ++i)
#pragma unroll
    for (int j = 0; j < 8; ++j) acc[i][j] = 0.f;

  const int xs_r = t >> 4;
  const int xs_c = (t & 15) * 4;
  const int ws_o = t & 63;
  const int ws_c = (t >> 6) * 4;
  const float* wrow;
  {
    const int o = o0 + ws_o;
    if (o < 32)      wrow = wq + (size_t)o * NC;
    else if (o < 64) wrow = wk + (size_t)(o - 32) * NC;
    else             wrow = wv + (size_t)(o - 64) * NC;
  }

  for (int c0 = 0; c0 < NC; c0 += 16) {
    __syncthreads();
    const float* xsrc = x + ((size_t)(b * NC + c0 + xs_r)) * NN + n0;
    *(float4*)&Xs[xs_r][xs_c]      = *(const float4*)(xsrc + xs_c);
    *(float4*)&Xs[xs_r][64 + xs_c] = *(const float4*)(xsrc + 64 + xs_c);
    {
      const float4 wv4 = *(const float4*)(wrow + c0 + ws_c);
      Ws[ws_c + 0][ws_o] = wv4.x;
      Ws[ws_c + 1][ws_o] = wv4.y;
      Ws[ws_c + 2][ws_o] = wv4.z;
      Ws[ws_c + 3][ws_o] = wv4.w;
    }
    __syncthreads();
#pragma unroll
    for (int cc = 0; cc < 16; ++cc) {
      const float4 wv4 = *(const float4*)&Ws[cc][og4 * 4];
      const float4 xa  = *(const float4*)&Xs[cc][ng * 8];
      const float4 xb  = *(const float4*)&Xs[cc][ng * 8 + 4];
      const float wvv[4] = {wv4.x, wv4.y, wv4.z, wv4.w};
      const float xaa[8] = {xa.x, xa.y, xa.z, xa.w, xb.x, xb.y, xb.z, xb.w};
#pragma unroll
      for (int i = 0; i < 4; ++i)
#pragma unroll
        for (int j = 0; j < 8; ++j) acc[i][j] += wvv[i] * xaa[j];
    }
  }

  if (blockIdx.y == 0) {
    float bb[4], sc[4];
#pragma unroll
    for (int i = 0; i < 4; ++i) {
      const int o = og4 * 4 + i;
      bb[i] = (o < 32) ? bq[o] : bk[o - 32];
      sc[i] = (o < 32) ? LOG2E : 1.0f;
    }
#pragma unroll
    for (int j = 0; j < 8; ++j) {
      union { ushort u[4]; uint2 v; } pk;
#pragma unroll
      for (int i = 0; i < 4; ++i) pk.u[i] = f2bf((acc[i][j] + bb[i]) * sc[i]);
      *(uint2*)(qk + ((size_t)(b * NN + n0 + ng * 8 + j)) * 64 + og4 * 4) = pk.v;
    }
  } else {
#pragma unroll
    for (int i = 0; i < 4; ++i) {
      const int c = o0 - 64 + og4 * 4 + i;
      const float bb = bv[c];
      union { ushort u[8]; uint4 v; } pk;
#pragma unroll
      for (int j = 0; j < 8; ++j) pk.u[j] = f2bf(acc[i][j] + bb);
      *(uint4*)(vt + ((size_t)(b * NC + c)) * NN + n0 + ng * 8) = pk.v;
    }
  }
}

// ---------------------------------------------------------------------------
// Flash attention, producer/consumer wave specialization.
// 256 blocks x 512 threads. Block = (b, 128 q-rows). j-chunk 256, 17
// intervals, ONE barrier each. P double-buffered (swizzled, 128 KB).
//  Waves 0-3 (S role): swapped mfma16(K,Q) for rows w*32..+32, exp2 (Q
//    pre-scaled), packed b64 P writes into P[iv&1]; then register-prefetch
//    K(iv+1). Interval 16: reduce row-sums -> lL.
//  Waves 4-7 (PV role): consume P[(iv-1)&1]: 32x32x16 MFMA, A = P rows
//    (all 128), B = V (64 channels per wave, pa shared across both 32-ch
//    halves -> LDS read amp 4x), V loaded inline (L2-resident, amp 1x).
// Each SIMD gets 1 S-wave + 1 PV-wave: exp/VALU runs against MFMA every
// cycle (true role split; setprio now applicable).
// ---------------------------------------------------------------------------
__global__ __launch_bounds__(512, 2)
void attn_kernel(const ushort* __restrict__ qk, const ushort* __restrict__ vt,
                 const float* __restrict__ x, const float* __restrict__ gamma,
                 float* __restrict__ out) {
  __shared__ __align__(16) ushort P[2][128 * 256];   // 128 KB, swizzled
  __shared__ __align__(16) float lL[128];

  const int lin  = blockIdx.x;
  const int b    = lin & 7;              // XCD swizzle: batch per XCD L2
  const int i0   = (lin >> 3) * 128;
  const int t    = threadIdx.x;
  const int w    = t >> 6;               // 0..7
  const int lane = t & 63;
  const int g16  = lane >> 4;
  const int c16  = lane & 15;
  const int l5   = lane >> 5;
  const int c32  = lane & 31;

  const f32x4 zero = {0.f, 0.f, 0.f, 0.f};
  const bool isS = (w < 4);

  // ---- S state ----
  const int prow0 = w * 32 + c16;        // valid for S waves
  const int prow1 = prow0 + 16;
  short8 qf0, qf1;
  short8 kf[16];
  float lp0 = 0.f, lp1 = 0.f;
  const ushort* kbase = qk + ((size_t)b * NN) * 64 + 32 + g16 * 8;
  if (isS) {
    qf0 = *(const short8*)(qk + ((size_t)(b * NN + i0 + prow0)) * 64 + g16 * 8);
    qf1 = *(const short8*)(qk + ((size_t)(b * NN + i0 + prow1)) * 64 + g16 * 8);
#pragma unroll
    for (int jt = 0; jt < 16; ++jt)
      kf[jt] = *(const short8*)(kbase + (size_t)(jt * 16 + c16) * 64);
  }

  // ---- PV state ----
  const int p = w - 4;                   // valid for PV waves
  f32x16 OA[4], OB[4];                   // [isub] x {ch-half A, B}
  const ushort* vbA = nullptr; const ushort* vbB = nullptr;
  if (!isS) {
#pragma unroll
    for (int isub = 0; isub < 4; ++isub)
#pragma unroll
      for (int e = 0; e < 16; ++e) { OA[isub][e] = 0.f; OB[isub][e] = 0.f; }
    vbA = vt + ((size_t)(b * NC + p * 64 + c32)) * NN + l5 * 8;
    vbB = vt + ((size_t)(b * NC + p * 64 + 32 + c32)) * NN + l5 * 8;
  }

  for (int iv = 0; iv <= NCH; ++iv) {
    if (isS) {
      if (iv < NCH) {
        ushort* Pb = P[iv & 1];
#pragma unroll
        for (int jt = 0; jt < 16; ++jt) {
          const f32x4 s0 = __builtin_amdgcn_mfma_f32_16x16x32_bf16(
              kf[jt], qf0, zero, 0, 0, 0);
          const f32x4 s1 = __builtin_amdgcn_mfma_f32_16x16x32_bf16(
              kf[jt], qf1, zero, 0, 0, 0);
          union { ushort u[4]; uint2 v; } pk0, pk1;
#pragma unroll
          for (int r = 0; r < 4; ++r) {
            const float e0 = exp2f(s0[r]);
            const float e1 = exp2f(s1[r]);
            lp0 += e0; lp1 += e1;
            pk0.u[r] = f2bf(e0); pk1.u[r] = f2bf(e1);
          }
          const int col = jt * 16 + g16 * 4;
          *(uint2*)&Pb[PIDX(prow0, col)] = pk0.v;
          *(uint2*)&Pb[PIDX(prow1, col)] = pk1.v;
        }
        // register-prefetch K for chunk iv+1 (lands under PV of this interval)
        if (iv + 1 < NCH) {
          const ushort* kb2 = kbase + (size_t)(iv + 1) * 256 * 64;
#pragma unroll
          for (int jt = 0; jt < 16; ++jt)
            kf[jt] = *(const short8*)(kb2 + (size_t)(jt * 16 + c16) * 64);
        }
      } else {
        // interval 16: finalize row sums (reduce over the 4 g16 groups)
        lp0 += __shfl_xor(lp0, 16); lp0 += __shfl_xor(lp0, 32);
        lp1 += __shfl_xor(lp1, 16); lp1 += __shfl_xor(lp1, 32);
        if (g16 == 0) { lL[prow0] = lp0; lL[prow1] = lp1; }
      }
    } else if (iv >= 1) {
      const int ch = iv - 1;
      const ushort* Pb = P[ch & 1];
      const int j0 = ch * 256;
      __builtin_amdgcn_s_setprio(1);
#pragma unroll
      for (int ji = 0; ji < 16; ++ji) {
        const int jo = ji * 16;
        const short8 vf0 = *(const short8*)(vbA + j0 + jo);
        const short8 vf1 = *(const short8*)(vbB + j0 + jo);
#pragma unroll
        for (int isub = 0; isub < 4; ++isub) {
          const short8 pa =
              *(const short8*)&Pb[PIDX(isub * 32 + c32, jo + l5 * 8)];
          OA[isub] = __builtin_amdgcn_mfma_f32_32x32x16_bf16(
              pa, vf0, OA[isub], 0, 0, 0);
          OB[isub] = __builtin_amdgcn_mfma_f32_32x32x16_bf16(
              pa, vf1, OB[isub], 0, 0, 0);
        }
      }
      __builtin_amdgcn_s_setprio(0);
    }
    __syncthreads();
  }

  // ---- epilogue: PV waves write out = gamma*O/l + x ----
  if (!isS) {
    const float g = gamma[0];
#pragma unroll
    for (int isub = 0; isub < 4; ++isub) {
#pragma unroll
      for (int q = 0; q < 4; ++q) {
        const int r0 = isub * 32 + q * 8 + l5 * 4;   // D row: (reg&3)+8q+4*l5
        const f32x4 li = *(const f32x4*)&lL[r0];
        f32x4 gi;
#pragma unroll
        for (int r = 0; r < 4; ++r) gi[r] = g / li[r];
        {
          const int c = p * 64 + c32;
          const size_t base = ((size_t)(b * NC + c)) * NN + i0 + r0;
          const f32x4 xv = *(const f32x4*)(x + base);
          f32x4 ov;
#pragma unroll
          for (int r = 0; r < 4; ++r) ov[r] = OA[isub][q * 4 + r] * gi[r] + xv[r];
          *(f32x4*)(out + base) = ov;
        }
        {
          const int c = p * 64 + 32 + c32;
          const size_t base = ((size_t)(b * NC + c)) * NN + i0 + r0;
          const f32x4 xv = *(const f32x4*)(x + base);
          f32x4 ov;
#pragma unroll
          for (int r = 0; r < 4; ++r) ov[r] = OB[isub][q * 4 + r] * gi[r] + xv[r];
          *(f32x4*)(out + base) = ov;
        }
      }
    }
  }
}

extern "C" void kernel_launch(void* const* d_in, const int* in_sizes, int n_in,
                              void* d_out, int out_size, void* d_ws, size_t ws_size,
                              hipStream_t stream) {
  const float* x  = (const float*)d_in[0];
  const float* wq = (const float*)d_in[1];
  const float* bq = (const float*)d_in[2];
  const float* wk = (const float*)d_in[3];
  const float* bk = (const float*)d_in[4];
  const float* wv = (const float*)d_in[5];
  const float* bv = (const float*)d_in[6];
  const float* gm = (const float*)d_in[7];
  float* outp = (float*)d_out;

  ushort* qkw = (ushort*)d_ws;                       // [B][N][64]  bf16, 4 MB
  ushort* vtw = qkw + (size_t)NB * NN * 64;          // [B][C][N]   bf16, 16 MB

  proj_kernel<<<dim3(NN / 128, 5, NB), 256, 0, stream>>>(
      x, wq, bq, wk, bk, wv, bv, qkw, vtw);
  attn_kernel<<<dim3((NN / 128) * NB), 512, 0, stream>>>(qkw, vtw, x, gm, outp);
}

// Round 10
// 180.694 us; speedup vs baseline: 2.8368x; 2.8368x over previous
//
#include <hip/hip_runtime.h>
#include <hip/hip_bf16.h>

typedef __attribute__((ext_vector_type(8))) short short8;   // 8 bf16 (4 VGPRs)
typedef __attribute__((ext_vector_type(4))) float f32x4;    // MFMA 16x16 C/D
typedef __attribute__((ext_vector_type(16))) float f32x16;  // MFMA 32x32 C/D

#define NB 8
#define NC 256
#define NN 4096
#define ND 32
#define NCH 16   // j-chunks of 256
#define LOG2E 1.44269504088896340736f

// P tile [2][128][256] ushort, 16B-slot XOR swizzle. row<<8 + (col^((row&15)<<3))
#define PIDX(row, col) (((row) << 8) + ((col) ^ (((row) & 15) << 3)))

static __device__ __forceinline__ ushort f2bf(float f) {
  __hip_bfloat16 h = __float2bfloat16(f);
  return reinterpret_cast<ushort&>(h);
}

// ---------------------------------------------------------------------------
// Projection (unchanged): fp32 MAC, bf16 out; Q pre-scaled by log2(e).
//   blockIdx.y==0 : o in [0,64)  -> QK[b][n][64]  (q 0..31, k 32..63)
//   blockIdx.y>=1 : o in [64,320)-> Vt[b][o-64][n]  (V transposed, bf16)
// ---------------------------------------------------------------------------
__global__ __launch_bounds__(256, 4)
void proj_kernel(const float* __restrict__ x,
                 const float* __restrict__ wq, const float* __restrict__ bq,
                 const float* __restrict__ wk, const float* __restrict__ bk,
                 const float* __restrict__ wv, const float* __restrict__ bv,
                 ushort* __restrict__ qk, ushort* __restrict__ vt) {
  __shared__ float Xs[16][128];
  __shared__ float Ws[16][64];
  const int n0 = blockIdx.x * 128;
  const int o0 = blockIdx.y * 64;
  const int b  = blockIdx.z;
  const int t  = threadIdx.x;
  const int og4 = t & 15;
  const int ng  = t >> 4;

  float acc[4][8];
#pragma unroll
  for (int i = 0; i < 4; ++i)
#pragma unroll
    for (int j = 0; j < 8; ++j) acc[i][j] = 0.f;

  const int xs_r = t >> 4;
  const int xs_c = (t & 15) * 4;
  const int ws_o = t & 63;
  const int ws_c = (t >> 6) * 4;
  const float* wrow;
  {
    const int o = o0 + ws_o;
    if (o < 32)      wrow = wq + (size_t)o * NC;
    else if (o < 64) wrow = wk + (size_t)(o - 32) * NC;
    else             wrow = wv + (size_t)(o - 64) * NC;
  }

  for (int c0 = 0; c0 < NC; c0 += 16) {
    __syncthreads();
    const float* xsrc = x + ((size_t)(b * NC + c0 + xs_r)) * NN + n0;
    *(float4*)&Xs[xs_r][xs_c]      = *(const float4*)(xsrc + xs_c);
    *(float4*)&Xs[xs_r][64 + xs_c] = *(const float4*)(xsrc + 64 + xs_c);
    {
      const float4 wv4 = *(const float4*)(wrow + c0 + ws_c);
      Ws[ws_c + 0][ws_o] = wv4.x;
      Ws[ws_c + 1][ws_o] = wv4.y;
      Ws[ws_c + 2][ws_o] = wv4.z;
      Ws[ws_c + 3][ws_o] = wv4.w;
    }
    __syncthreads();
#pragma unroll
    for (int cc = 0; cc < 16; ++cc) {
      const float4 wv4 = *(const float4*)&Ws[cc][og4 * 4];
      const float4 xa  = *(const float4*)&Xs[cc][ng * 8];
      const float4 xb  = *(const float4*)&Xs[cc][ng * 8 + 4];
      const float wvv[4] = {wv4.x, wv4.y, wv4.z, wv4.w};
      const float xaa[8] = {xa.x, xa.y, xa.z, xa.w, xb.x, xb.y, xb.z, xb.w};
#pragma unroll
      for (int i = 0; i < 4; ++i)
#pragma unroll
        for (int j = 0; j < 8; ++j) acc[i][j] += wvv[i] * xaa[j];
    }
  }

  if (blockIdx.y == 0) {
    float bb[4], sc[4];
#pragma unroll
    for (int i = 0; i < 4; ++i) {
      const int o = og4 * 4 + i;
      bb[i] = (o < 32) ? bq[o] : bk[o - 32];
      sc[i] = (o < 32) ? LOG2E : 1.0f;
    }
#pragma unroll
    for (int j = 0; j < 8; ++j) {
      union { ushort u[4]; uint2 v; } pk;
#pragma unroll
      for (int i = 0; i < 4; ++i) pk.u[i] = f2bf((acc[i][j] + bb[i]) * sc[i]);
      *(uint2*)(qk + ((size_t)(b * NN + n0 + ng * 8 + j)) * 64 + og4 * 4) = pk.v;
    }
  } else {
#pragma unroll
    for (int i = 0; i < 4; ++i) {
      const int c = o0 - 64 + og4 * 4 + i;
      const float bb = bv[c];
      union { ushort u[8]; uint4 v; } pk;
#pragma unroll
      for (int j = 0; j < 8; ++j) pk.u[j] = f2bf(acc[i][j] + bb);
      *(uint4*)(vt + ((size_t)(b * NC + c)) * NN + n0 + ng * 8) = pk.v;
    }
  }
}

// ---------------------------------------------------------------------------
// Flash attention, producer/consumer wave specialization (R9 retry, spill
// fixed: launch_bounds(512,1) -> 256-VGPR budget; S-state kf[8] not kf[16]).
// 256 blocks x 512 threads. Block = (b, 128 q-rows). j-chunk 256, 17
// intervals, ONE barrier each. P double-buffered (swizzled, 128 KB).
//  Waves 0-3 (S): swapped mfma16(K,Q) for rows w*32..+32, exp2, packed b64
//    P writes into P[iv&1]. K loaded in two half-chunk passes (kf[8]).
//    Interval 16: reduce row-sums -> lL.
//  Waves 4-7 (PV): consume P[(iv-1)&1]: 32x32x16 MFMA, A = P rows (all
//    128), B = V (64 ch/wave), V inline (L2-resident).
// Each SIMD: 1 S-wave + 1 PV-wave -> exp/VALU co-issues against MFMA.
// ---------------------------------------------------------------------------
__global__ __launch_bounds__(512, 1)
void attn_kernel(const ushort* __restrict__ qk, const ushort* __restrict__ vt,
                 const float* __restrict__ x, const float* __restrict__ gamma,
                 float* __restrict__ out) {
  __shared__ __align__(16) ushort P[2][128 * 256];   // 128 KB, swizzled
  __shared__ __align__(16) float lL[128];

  const int lin  = blockIdx.x;
  const int b    = lin & 7;              // XCD swizzle: batch per XCD L2
  const int i0   = (lin >> 3) * 128;
  const int t    = threadIdx.x;
  const int w    = t >> 6;               // 0..7
  const int lane = t & 63;
  const int g16  = lane >> 4;
  const int c16  = lane & 15;
  const int l5   = lane >> 5;
  const int c32  = lane & 31;

  const f32x4 zero = {0.f, 0.f, 0.f, 0.f};
  const bool isS = (w < 4);

  // ---- S state (waves 0-3) ----
  const int prow0 = w * 32 + c16;
  const int prow1 = prow0 + 16;
  short8 qf0, qf1;
  short8 kf[8];
  float lp0 = 0.f, lp1 = 0.f;
  const ushort* kbase = qk + ((size_t)b * NN) * 64 + 32 + g16 * 8;
  if (isS) {
    qf0 = *(const short8*)(qk + ((size_t)(b * NN + i0 + prow0)) * 64 + g16 * 8);
    qf1 = *(const short8*)(qk + ((size_t)(b * NN + i0 + prow1)) * 64 + g16 * 8);
  }

  // ---- PV state (waves 4-7) ----
  const int p = w - 4;
  f32x16 OA[4], OB[4];
  const ushort* vbA = nullptr; const ushort* vbB = nullptr;
  if (!isS) {
#pragma unroll
    for (int isub = 0; isub < 4; ++isub)
#pragma unroll
      for (int e = 0; e < 16; ++e) { OA[isub][e] = 0.f; OB[isub][e] = 0.f; }
    vbA = vt + ((size_t)(b * NC + p * 64 + c32)) * NN + l5 * 8;
    vbB = vt + ((size_t)(b * NC + p * 64 + 32 + c32)) * NN + l5 * 8;
  }

  for (int iv = 0; iv <= NCH; ++iv) {
    if (isS) {
      if (iv < NCH) {
        ushort* Pb = P[iv & 1];
        const ushort* kch = kbase + (size_t)iv * 256 * 64;
#pragma unroll
        for (int h = 0; h < 2; ++h) {
          // load this half-chunk's K fragments (8 x short8 = 32 VGPR)
#pragma unroll
          for (int jt = 0; jt < 8; ++jt)
            kf[jt] = *(const short8*)(
                kch + (size_t)(h * 128 + jt * 16 + c16) * 64);
#pragma unroll
          for (int jt = 0; jt < 8; ++jt) {
            const f32x4 s0 = __builtin_amdgcn_mfma_f32_16x16x32_bf16(
                kf[jt], qf0, zero, 0, 0, 0);
            const f32x4 s1 = __builtin_amdgcn_mfma_f32_16x16x32_bf16(
                kf[jt], qf1, zero, 0, 0, 0);
            union { ushort u[4]; uint2 v; } pk0, pk1;
#pragma unroll
            for (int r = 0; r < 4; ++r) {
              const float e0 = exp2f(s0[r]);
              const float e1 = exp2f(s1[r]);
              lp0 += e0; lp1 += e1;
              pk0.u[r] = f2bf(e0); pk1.u[r] = f2bf(e1);
            }
            const int col = h * 128 + jt * 16 + g16 * 4;
            *(uint2*)&Pb[PIDX(prow0, col)] = pk0.v;
            *(uint2*)&Pb[PIDX(prow1, col)] = pk1.v;
          }
        }
      } else {
        // interval 16: finalize row sums (reduce over the 4 g16 groups)
        lp0 += __shfl_xor(lp0, 16); lp0 += __shfl_xor(lp0, 32);
        lp1 += __shfl_xor(lp1, 16); lp1 += __shfl_xor(lp1, 32);
        if (g16 == 0) { lL[prow0] = lp0; lL[prow1] = lp1; }
      }
    } else if (iv >= 1) {
      const int ch = iv - 1;
      const ushort* Pb = P[ch & 1];
      const int j0 = ch * 256;
      __builtin_amdgcn_s_setprio(1);
#pragma unroll
      for (int ji = 0; ji < 16; ++ji) {
        const int jo = ji * 16;
        const short8 vf0 = *(const short8*)(vbA + j0 + jo);
        const short8 vf1 = *(const short8*)(vbB + j0 + jo);
#pragma unroll
        for (int isub = 0; isub < 4; ++isub) {
          const short8 pa =
              *(const short8*)&Pb[PIDX(isub * 32 + c32, jo + l5 * 8)];
          OA[isub] = __builtin_amdgcn_mfma_f32_32x32x16_bf16(
              pa, vf0, OA[isub], 0, 0, 0);
          OB[isub] = __builtin_amdgcn_mfma_f32_32x32x16_bf16(
              pa, vf1, OB[isub], 0, 0, 0);
        }
      }
      __builtin_amdgcn_s_setprio(0);
    }
    __syncthreads();
  }

  // ---- epilogue: PV waves write out = gamma*O/l + x ----
  if (!isS) {
    const float g = gamma[0];
#pragma unroll
    for (int isub = 0; isub < 4; ++isub) {
#pragma unroll
      for (int q = 0; q < 4; ++q) {
        const int r0 = isub * 32 + q * 8 + l5 * 4;   // D row: (reg&3)+8q+4*l5
        const f32x4 li = *(const f32x4*)&lL[r0];
        f32x4 gi;
#pragma unroll
        for (int r = 0; r < 4; ++r) gi[r] = g / li[r];
        {
          const int c = p * 64 + c32;
          const size_t base = ((size_t)(b * NC + c)) * NN + i0 + r0;
          const f32x4 xv = *(const f32x4*)(x + base);
          f32x4 ov;
#pragma unroll
          for (int r = 0; r < 4; ++r) ov[r] = OA[isub][q * 4 + r] * gi[r] + xv[r];
          *(f32x4*)(out + base) = ov;
        }
        {
          const int c = p * 64 + 32 + c32;
          const size_t base = ((size_t)(b * NC + c)) * NN + i0 + r0;
          const f32x4 xv = *(const f32x4*)(x + base);
          f32x4 ov;
#pragma unroll
          for (int r = 0; r < 4; ++r) ov[r] = OB[isub][q * 4 + r] * gi[r] + xv[r];
          *(f32x4*)(out + base) = ov;
        }
      }
    }
  }
}

extern "C" void kernel_launch(void* const* d_in, const int* in_sizes, int n_in,
                              void* d_out, int out_size, void* d_ws, size_t ws_size,
                              hipStream_t stream) {
  const float* x  = (const float*)d_in[0];
  const float* wq = (const float*)d_in[1];
  const float* bq = (const float*)d_in[2];
  const float* wk = (const float*)d_in[3];
  const float* bk = (const float*)d_in[4];
  const float* wv = (const float*)d_in[5];
  const float* bv = (const float*)d_in[6];
  const float* gm = (const float*)d_in[7];
  float* outp = (float*)d_out;

  ushort* qkw = (ushort*)d_ws;                       // [B][N][64]  bf16, 4 MB
  ushort* vtw = qkw + (size_t)NB * NN * 64;          // [B][C][N]   bf16, 16 MB

  proj_kernel<<<dim3(NN / 128, 5, NB), 256, 0, stream>>>(
      x, wq, bq, wk, bk, wv, bv, qkw, vtw);
  attn_kernel<<<dim3((NN / 128) * NB), 512, 0, stream>>>(qkw, vtw, x, gm, outp);
}